// Round 1
// baseline (240.460 us; speedup 1.0000x reference)
//
#include <hip/hip_runtime.h>
#include <math.h>

// Problem constants (match reference)
#define B_SZ 16384
#define C_SZ 10
#define K_SZ 64
#define E_SZ 128

__global__ __launch_bounds__(256) void w2v_loss_kernel(
    const int* __restrict__ inout_labels,   // [B]
    const int* __restrict__ near_labels,    // [B, C]
    const int* __restrict__ neg_labels,     // [B, K]
    const float* __restrict__ in_embed,     // [V, E]
    const float* __restrict__ out_embed,    // [V, E]
    float* __restrict__ out)                // [B]
{
    const int b    = blockIdx.x;
    const int tid  = threadIdx.x;
    const int lane = tid & 63;
    const int wave = tid >> 6;   // 0..3

    __shared__ float wave_sums[4];

    // Input embedding: each lane keeps 2 floats in registers (coalesced 512B row read).
    const int row_in = inout_labels[b];
    const float2 u = *reinterpret_cast<const float2*>(
        in_embed + (size_t)row_in * E_SZ + lane * 2);

    float acc = 0.0f;

    // 74 rows (10 near + 64 neg) distributed round-robin over 4 waves.
    for (int j = wave; j < C_SZ + K_SZ; j += 4) {
        int row;
        float sgn;
        if (j < C_SZ) {
            row = near_labels[b * C_SZ + j];
            sgn = 1.0f;
        } else {
            row = neg_labels[b * K_SZ + (j - C_SZ)];
            sgn = -1.0f;
        }
        const float2 v = *reinterpret_cast<const float2*>(
            out_embed + (size_t)row * E_SZ + lane * 2);

        float p = u.x * v.x + u.y * v.y;
        // wave64 butterfly reduce -> all lanes hold full dot product
        #pragma unroll
        for (int off = 32; off >= 1; off >>= 1)
            p += __shfl_xor(p, off, 64);

        const float x = sgn * p;
        // stable logsigmoid(x) = min(x,0) - log1p(exp(-|x|))
        const float ls = fminf(x, 0.0f) - log1pf(__expf(-fabsf(x)));
        acc += ls;   // uniform across lanes after full reduce
    }

    if (lane == 0) wave_sums[wave] = acc;
    __syncthreads();
    if (tid == 0) {
        out[b] = -(wave_sums[0] + wave_sums[1] + wave_sums[2] + wave_sums[3]);
    }
}

extern "C" void kernel_launch(void* const* d_in, const int* in_sizes, int n_in,
                              void* d_out, int out_size, void* d_ws, size_t ws_size,
                              hipStream_t stream) {
    const int*   inout_labels = (const int*)d_in[0];
    const int*   near_labels  = (const int*)d_in[1];
    const int*   neg_labels   = (const int*)d_in[2];
    const float* in_embed     = (const float*)d_in[3];
    const float* out_embed    = (const float*)d_in[4];
    float*       out          = (float*)d_out;

    w2v_loss_kernel<<<B_SZ, 256, 0, stream>>>(
        inout_labels, near_labels, neg_labels, in_embed, out_embed, out);
}

// Round 2
// 86.873 us; speedup vs baseline: 2.7680x; 2.7680x over previous
//
#include <hip/hip_runtime.h>
#include <math.h>

// Problem constants (match reference)
#define B_SZ 16384
#define C_SZ 10
#define K_SZ 64
#define E_SZ 128
#define NROWS (C_SZ + K_SZ)   // 74

// One wave (64 lanes) per batch element; 4 waves (4 batch elems) per block.
// Within a wave: 8 groups of 8 lanes; each group owns one embedding row per
// pass. 8 lanes x float4 = 32 floats/iter, 4 iters = 128 = E. Each global
// load instruction touches exactly 8 distinct 128B cache lines (one per row).
__global__ __launch_bounds__(256) void w2v_loss_kernel(
    const int* __restrict__ inout_labels,   // [B]
    const int* __restrict__ near_labels,    // [B, C]
    const int* __restrict__ neg_labels,     // [B, K]
    const float* __restrict__ in_embed,     // [V, E]
    const float* __restrict__ out_embed,    // [V, E]
    float* __restrict__ out)                // [B]
{
    const int tid  = threadIdx.x;
    const int lane = tid & 63;
    const int wave = tid >> 6;                 // 0..3
    const int b    = blockIdx.x * 4 + wave;    // batch element
    const int r    = lane >> 3;                // row-in-pass group 0..7
    const int e    = lane & 7;                 // element group 0..7

    // ---- input embedding: each lane holds the 16 floats it needs ----
    // lane uses u[i*32 + e*4 .. +3] for i = 0..3
    const int row_in = inout_labels[b];
    const float4* up = reinterpret_cast<const float4*>(in_embed + (size_t)row_in * E_SZ);
    float4 u0 = up[0 * 8 + e];
    float4 u1 = up[1 * 8 + e];
    float4 u2 = up[2 * 8 + e];
    float4 u3 = up[3 * 8 + e];

    const int* nearb = near_labels + b * C_SZ;
    const int* negb  = neg_labels  + b * K_SZ;

    float acc = 0.0f;

    // 74 rows in 10 passes of 8 rows (last pass: 2 active groups)
    #pragma unroll 2
    for (int p = 0; p < 10; ++p) {
        const int j = p * 8 + r;               // row index 0..79
        const bool active = (j < NROWS);
        // label (clamped for inactive lanes -> harmless row-0 read)
        int lbl;
        float sgn;
        if (j < C_SZ)       { lbl = nearb[j];                 sgn = 1.0f; }
        else if (active)    { lbl = negb[j - C_SZ];           sgn = -1.0f; }
        else                { lbl = 0;                        sgn = -1.0f; }

        const float4* vp = reinterpret_cast<const float4*>(out_embed + (size_t)lbl * E_SZ);
        float4 v0 = vp[0 * 8 + e];
        float4 v1 = vp[1 * 8 + e];
        float4 v2 = vp[2 * 8 + e];
        float4 v3 = vp[3 * 8 + e];

        float s = u0.x * v0.x + u0.y * v0.y + u0.z * v0.z + u0.w * v0.w;
        s += u1.x * v1.x + u1.y * v1.y + u1.z * v1.z + u1.w * v1.w;
        s += u2.x * v2.x + u2.y * v2.y + u2.z * v2.z + u2.w * v2.w;
        s += u3.x * v3.x + u3.y * v3.y + u3.z * v3.z + u3.w * v3.w;

        // reduce across the 8-lane group (xor 1,2,4 stays inside the group)
        s += __shfl_xor(s, 1, 64);
        s += __shfl_xor(s, 2, 64);
        s += __shfl_xor(s, 4, 64);

        const float x = sgn * s;
        // fast stable logsigmoid(x) = min(x,0) - log(1 + exp(-|x|))
        const float ls = fminf(x, 0.0f) - __logf(1.0f + __expf(-fabsf(x)));
        acc += active ? ls : 0.0f;
    }

    // every lane in an e-column holds identical per-group sums; reduce over r
    acc += __shfl_xor(acc, 8, 64);
    acc += __shfl_xor(acc, 16, 64);
    acc += __shfl_xor(acc, 32, 64);

    if (lane == 0) out[b] = -acc;
}

extern "C" void kernel_launch(void* const* d_in, const int* in_sizes, int n_in,
                              void* d_out, int out_size, void* d_ws, size_t ws_size,
                              hipStream_t stream) {
    const int*   inout_labels = (const int*)d_in[0];
    const int*   near_labels  = (const int*)d_in[1];
    const int*   neg_labels   = (const int*)d_in[2];
    const float* in_embed     = (const float*)d_in[3];
    const float* out_embed    = (const float*)d_in[4];
    float*       out          = (float*)d_out;

    w2v_loss_kernel<<<B_SZ / 4, 256, 0, stream>>>(
        inout_labels, near_labels, neg_labels, in_embed, out_embed, out);
}